// Round 4
// baseline (20897.981 us; speedup 1.0000x reference)
//
#include <hip/hip_runtime.h>
#include <hip/hip_bf16.h>

// EncoderBiLSTMMaxPool — round 4: paired-CU recurrence.
// Each of the 8 streams (chain q, dir d) is split across TWO WGs (units 0-127 / 128-255).
// Thread = one gate row, all 256 k-weights in 128 VGPRs (no LDS weights, no spill).
// Pair exchanges 128 h values (f16) per step via global memory + per-wave release/acquire flags.
// Pairing (s, s+8) targets same-XCD L2; protocol is device-scope correct regardless of placement.

typedef _Float16 f16;
typedef _Float16 h2_t  __attribute__((ext_vector_type(2)));
typedef _Float16 f16x8 __attribute__((ext_vector_type(8)));
typedef float    f32x4 __attribute__((ext_vector_type(4)));

#define B_  128
#define S_  128
#define H_  512
#define HH_ 256
#define M_  (B_ * S_)   // 16384
#define NG  1024        // gates per direction (4*HH)
#define K0  512         // LSTM input dim

__device__ __forceinline__ float sigmoidf_(float x) { return 1.0f / (1.0f + __expf(-x)); }
__device__ __forceinline__ float tanhf_(float x)    { return 1.0f - 2.0f / (__expf(2.0f * x) + 1.0f); }

__device__ __forceinline__ float ldf(const void* p, long i, int isbf) {
    return isbf ? __bfloat162float(((const __hip_bfloat16*)p)[i]) : ((const float*)p)[i];
}

__device__ __forceinline__ float dot2f(int w, int h, float acc) {
#if __has_builtin(__builtin_amdgcn_fdot2)
    return __builtin_amdgcn_fdot2(__builtin_bit_cast(h2_t, w), __builtin_bit_cast(h2_t, h), acc, false);
#else
    h2_t a = __builtin_bit_cast(h2_t, w), b = __builtin_bit_cast(h2_t, h);
    return acc + (float)a[0] * (float)b[0] + (float)a[1] * (float)b[1];
#endif
}

// ---------------- dtype detection (bf16 vs fp32 input buffers) ----------------
__global__ void k_detect(const unsigned short* __restrict__ e, int* __restrict__ flag) {
    __shared__ int cnt;
    if (threadIdx.x == 0) cnt = 0;
    __syncthreads();
    unsigned short v = e[threadIdx.x];
    int ex = (v >> 7) & 0xFF;
    if (ex >= 100 && ex < 127) atomicAdd(&cnt, 1);
    __syncthreads();
    if (threadIdx.x == 0) *flag = (cnt >= 200) ? 1 : 0;   // 1 = bf16, 0 = fp32
}

// ---------------- embedding ----------------
__global__ void k_embed(const int* __restrict__ rt, const int* __restrict__ re, const int* __restrict__ rm,
                        const void* __restrict__ Ert, const void* __restrict__ Ere,
                        const void* __restrict__ Erm, f16* __restrict__ emb,
                        const int* __restrict__ flag) {
    const int isbf = *flag;
    int gid = blockIdx.x * 256 + threadIdx.x;      // < 16384*512
    int bs = gid >> 9, h = gid & 511;
    float v = ldf(Ert, (long)rt[bs] * H_ + h, isbf)
            + ldf(Ere, (long)re[bs] * H_ + h, isbf)
            + ldf(Erm, (long)rm[bs] * H_ + h, isbf);
    emb[gid] = (f16)v;
}

// ---------------- weight conversion -> f16, bias = bih+bhh (f32), zero sync flags ----------------
__global__ void k_wconv(const void* __restrict__ Wih, const void* __restrict__ Whh,
                        const void* __restrict__ bih, const void* __restrict__ bhh,
                        f16* __restrict__ wih, f16* __restrict__ whh, float* __restrict__ bias,
                        const int* __restrict__ flag, int* __restrict__ fsync) {
    const int isbf = *flag;
    int gid = blockIdx.x * 256 + threadIdx.x;      // < 2,097,152
    wih[gid] = (f16)ldf(Wih, gid, isbf);
    if (gid < 1048576) whh[gid] = (f16)ldf(Whh, gid, isbf);
    if (gid < 4096)    bias[gid] = ldf(bih, gid, isbf) + ldf(bhh, gid, isbf);
    if (gid < 64)      fsync[gid] = 0;
}

// ---------------- GEMM: C[16384][2048] = A[16384][512] * W[2048][512]^T (f16, fp32 acc) ----------------
__global__ __launch_bounds__(256) void k_gemm(const f16* __restrict__ A, const f16* __restrict__ Bm,
                                              f16* __restrict__ C) {
    const int bm = blockIdx.x & 127;
    const int bn = blockIdx.x >> 7;
    const int tid = threadIdx.x;
    const int lane = tid & 63, wave = tid >> 6;
    const int wm = wave & 1, wn = wave >> 1;
    __shared__ __align__(16) f16 As[128][72];
    __shared__ __align__(16) f16 Bs[128][72];
    f32x4 acc[4][4];
#pragma unroll
    for (int i = 0; i < 4; ++i)
#pragma unroll
        for (int jj = 0; jj < 4; ++jj) acc[i][jj] = (f32x4){0.f, 0.f, 0.f, 0.f};
    const long abase = (long)bm * 128 * K0;
    const long bbase = (long)bn * 128 * K0;
    for (int kt = 0; kt < K0; kt += 64) {
#pragma unroll
        for (int p = 0; p < 4; ++p) {
            int r = p * 32 + (tid >> 3), s = tid & 7;
            *(int4*)&As[r][s * 8] = *(const int4*)(A  + abase + (long)r * K0 + kt + s * 8);
            *(int4*)&Bs[r][s * 8] = *(const int4*)(Bm + bbase + (long)r * K0 + kt + s * 8);
        }
        __syncthreads();
        const int quad = lane >> 4, l15 = lane & 15;
#pragma unroll
        for (int kc = 0; kc < 64; kc += 32) {
            f16x8 af[4], bf[4];
#pragma unroll
            for (int mt = 0; mt < 4; ++mt) af[mt] = *(const f16x8*)&As[wm * 64 + mt * 16 + l15][kc + quad * 8];
#pragma unroll
            for (int nt = 0; nt < 4; ++nt) bf[nt] = *(const f16x8*)&Bs[wn * 64 + nt * 16 + l15][kc + quad * 8];
#pragma unroll
            for (int mt = 0; mt < 4; ++mt)
#pragma unroll
                for (int nt = 0; nt < 4; ++nt)
                    acc[mt][nt] = __builtin_amdgcn_mfma_f32_16x16x32_f16(af[mt], bf[nt], acc[mt][nt], 0, 0, 0);
        }
        __syncthreads();
    }
    const int quad = lane >> 4, l15 = lane & 15;
#pragma unroll
    for (int mt = 0; mt < 4; ++mt)
#pragma unroll
        for (int nt = 0; nt < 4; ++nt)
#pragma unroll
            for (int r = 0; r < 4; ++r) {
                int row = bm * 128 + wm * 64 + mt * 16 + quad * 4 + r;
                int col = bn * 128 + wn * 64 + nt * 16 + l15;
                C[(long)row * 2048 + col] = (f16)acc[mt][nt][r];
            }
}

// ---------------- recurrence: 16 WGs = (wgHalf, stream s); stream s handled by blocks s and s+8.
// 512 threads: thread (g = tid>>7, j = tid&127) owns gate row g*256+u (u = wgHalf*128+j), k=0..255
// entirely in 32 int4 VGPRs. h exchange: LDS for own half, global+flags for peer half. ----------------
__global__ __launch_bounds__(512, 1) void k_recur(
    const f16* __restrict__ xp,    // [16384][2048] input projections (no bias)
    const f16* __restrict__ whh,   // [2][2][1024][256] f16
    const float* __restrict__ bias,// [2][2][1024]
    const void* __restrict__ h0, const void* __restrict__ c0,
    f16* __restrict__ yf16,        // layer0 out [16384][512]
    void* __restrict__ yout,       // layer1 out (d_out bilstm region)
    int layer, const int* __restrict__ flag,
    f16* __restrict__ hxg,         // [2][8][2][2][128] f16 pair-exchange slots
    int* __restrict__ fsync) {     // [2][8][2][2] per-wave step flags
    const int isbf = *flag;
    const int s = blockIdx.x & 7, wgHalf = blockIdx.x >> 3;
    const int q = s >> 1, d = s & 1;
    const int tid = threadIdx.x;
    const int g = tid >> 7, j = tid & 127;
    const int u = wgHalf * 128 + j;
    const int ld = layer * 2 + d;
    const int ownC = wgHalf * 16, peerC = 16 - ownC;   // int4-chunk bases into hbuf

    __shared__ __align__(16) f16 hbuf[256];
    __shared__ float plds[3][128];

    // weights: row (g*256+u); own-half ks first, then peer-half ks
    int4 w[32];
    {
        const f16* wr = whh + ((long)ld * NG + g * 256 + u) * 256;
        const int4* wo = (const int4*)(wr + wgHalf * 128);
        const int4* wp = (const int4*)(wr + (1 - wgHalf) * 128);
#pragma unroll
        for (int c = 0; c < 16; ++c) w[c] = wo[c];
#pragma unroll
        for (int c = 0; c < 16; ++c) w[16 + c] = wp[c];
    }
    const float bs = bias[ld * NG + g * 256 + u];

    f16*       hx_mine = hxg + (((long)layer * 8 + s) * 2 + wgHalf) * 256;
    const f16* hx_peer = hxg + (((long)layer * 8 + s) * 2 + (1 - wgHalf)) * 256;
    int* fl_mine = fsync + ((layer * 8 + s) * 2 + wgHalf) * 2;
    int* fl_peer = fsync + ((layer * 8 + s) * 2 + (1 - wgHalf)) * 2;

    float cst = 0.f;
    if (g == 0) cst = (q == 0) ? ldf(c0, ld * 256 + u, isbf) : 0.f;
    if (tid < 256) {                                   // init full h (both halves)
        float hv = (q == 0) ? ldf(h0, ld * 256 + tid, isbf) : 0.f;
        hbuf[tid] = (f16)hv;
    }
    __syncthreads();

    float hn_prev = 0.f;
    long  oidx_prev = -1;
    int   dead = 0;
    for (int t = 0; t < 4096; ++t) {
        const int b = q * 32 + (t >> 7);
        const int ti = t & 127;
        const int tt = d ? (127 - ti) : ti;
        // deferred y store from previous step (ack absorbed by later barriers)
        if (g == 0 && oidx_prev >= 0) {
            if (layer == 0)      yf16[oidx_prev] = (f16)hn_prev;
            else if (isbf)       ((__hip_bfloat16*)yout)[oidx_prev] = __float2bfloat16(hn_prev);
            else                 ((float*)yout)[oidx_prev] = hn_prev;
        }
        // xp prefetch (consumed after phase 2)
        const f16 xh = xp[((long)b * 128 + tt) * 2048 + d * NG + g * 256 + u];

        // wave 0: wait for peer's step-t h, then issue the 256B staging load
        int4 pv;
        if (t > 0 && tid < 64 && !dead) {
            int iters = 0;
            for (;;) {
                int f0 = 0, f1 = 0;
                if (tid == 0) {
                    f0 = __hip_atomic_load(&fl_peer[0], __ATOMIC_ACQUIRE, __HIP_MEMORY_SCOPE_AGENT);
                    f1 = __hip_atomic_load(&fl_peer[1], __ATOMIC_ACQUIRE, __HIP_MEMORY_SCOPE_AGENT);
                }
                f0 = __builtin_amdgcn_readfirstlane(f0);
                f1 = __builtin_amdgcn_readfirstlane(f1);
                if (f0 >= t && f1 >= t) break;
                if (++iters > (1 << 20)) { dead = 1; break; }   // bail: no hang, bench will fail
                __builtin_amdgcn_s_sleep(1);
            }
        }
        if (t > 0 && tid < 16) pv = ((const int4*)(hx_peer + (t & 1) * 128))[tid];

        // phase 1: own-half k (peer staging load in flight)
        float a = bs;
        const int4* hp = (const int4*)hbuf;
#pragma unroll
        for (int c = 0; c < 16; ++c) {
            int4 hh = hp[ownC + c];
            a = dot2f(w[c].x, hh.x, a); a = dot2f(w[c].y, hh.y, a);
            a = dot2f(w[c].z, hh.z, a); a = dot2f(w[c].w, hh.w, a);
        }
        if (t > 0 && tid < 16) ((int4*)hbuf)[peerC + tid] = pv;
        __syncthreads();                                // B1: peer half staged
        // phase 2: peer-half k
#pragma unroll
        for (int c = 0; c < 16; ++c) {
            int4 hh = hp[peerC + c];
            a = dot2f(w[16 + c].x, hh.x, a); a = dot2f(w[16 + c].y, hh.y, a);
            a = dot2f(w[16 + c].z, hh.z, a); a = dot2f(w[16 + c].w, hh.w, a);
        }
        a += (float)xh;
        if (g) plds[g - 1][j] = a;
        __syncthreads();                                // B2: preacts exchanged
        if (g == 0) {
            float ig = sigmoidf_(a);
            float fg = sigmoidf_(plds[0][j]);
            float gg = tanhf_(plds[1][j]);
            float og = sigmoidf_(plds[2][j]);
            cst = fg * cst + ig * gg;
            float hn = og * tanhf_(cst);
            hbuf[u] = (f16)hn;                          // own half for next step
            hx_mine[((t + 1) & 1) * 128 + j] = (f16)hn; // peer's copy
            __hip_atomic_store(&fl_mine[tid >> 6], t + 1, __ATOMIC_RELEASE, __HIP_MEMORY_SCOPE_AGENT);
            hn_prev = hn;
            oidx_prev = ((long)b * 128 + tt) * 512 + d * 256 + u;
        }
        __syncthreads();                                // B3: hbuf write visible
    }
    // final deferred y store
    if (g == 0 && oidx_prev >= 0) {
        if (layer == 0)      yf16[oidx_prev] = (f16)hn_prev;
        else if (isbf)       ((__hip_bfloat16*)yout)[oidx_prev] = __float2bfloat16(hn_prev);
        else                 ((float*)yout)[oidx_prev] = hn_prev;
    }
}

// ---------------- max over batch axis ----------------
__global__ void k_maxpool(const void* __restrict__ bil, void* __restrict__ outbase,
                          const int* __restrict__ flag) {
    const int isbf = *flag;
    int gid = blockIdx.x * 256 + threadIdx.x;      // s*512+h, < 65536
    float m = -1e30f;
    for (int b = 0; b < 128; ++b)
        m = fmaxf(m, ldf(bil, (long)b * 65536 + gid, isbf));
    long o = (long)M_ * H_ + gid;
    if (isbf) ((__hip_bfloat16*)outbase)[o] = __float2bfloat16(m);
    else      ((float*)outbase)[o] = m;
}

extern "C" void kernel_launch(void* const* d_in, const int* in_sizes, int n_in,
                              void* d_out, int out_size, void* d_ws, size_t ws_size,
                              hipStream_t stream) {
    const int* rt = (const int*)d_in[0];
    const int* re = (const int*)d_in[1];
    const int* rm = (const int*)d_in[2];
    const void* h0  = d_in[3];
    const void* c0  = d_in[4];
    const void* Ert = d_in[5];
    const void* Ere = d_in[6];
    const void* Erm = d_in[7];
    const void* Wih = d_in[8];
    const void* Whh = d_in[9];
    const void* bih = d_in[10];
    const void* bhh = d_in[11];

    if (ws_size < 107000000u) return;

    char* ws = (char*)d_ws;
    f16*   emb   = (f16*)(ws);                     // 16,777,216 B
    f16*   wih   = (f16*)(ws + 16777216);          //  4,194,304 B  [2][2][1024][512]
    f16*   whh   = (f16*)(ws + 20971520);          //  2,097,152 B  [2][2][1024][256]
    float* bias  = (float*)(ws + 23068672);        //     16,384 B  [2][2][1024]
    f16*   xpb   = (f16*)(ws + 23085056);          // 67,108,864 B  [16384][2048]
    f16*   y0    = (f16*)(ws + 90193920);          // 16,777,216 B  [16384][512]
    int*   flag  = (int*)(ws + 106971136);         //          4 B
    int*   fsync = (int*)(ws + 106971200);         //        256 B  [2][8][2][2]
    f16*   hxg   = (f16*)(ws + 106971520);         //     16,384 B  [2][8][2][2][128]

    hipLaunchKernelGGL(k_detect, dim3(1),     dim3(256), 0, stream, (const unsigned short*)Ert, flag);
    hipLaunchKernelGGL(k_embed,  dim3(32768), dim3(256), 0, stream, rt, re, rm, Ert, Ere, Erm, emb, flag);
    hipLaunchKernelGGL(k_wconv,  dim3(8192),  dim3(256), 0, stream, Wih, Whh, bih, bhh, wih, whh, bias, flag, fsync);
    hipLaunchKernelGGL(k_gemm,   dim3(2048),  dim3(256), 0, stream, emb, wih, xpb);
    hipLaunchKernelGGL(k_recur,  dim3(16),    dim3(512), 0, stream, xpb, whh, bias, h0, c0, y0, d_out, 0, flag, hxg, fsync);
    hipLaunchKernelGGL(k_gemm,   dim3(2048),  dim3(256), 0, stream, y0, wih + (long)2 * NG * K0, xpb);
    hipLaunchKernelGGL(k_recur,  dim3(16),    dim3(512), 0, stream, xpb, whh, bias, h0, c0, y0, d_out, 1, flag, hxg, fsync);
    hipLaunchKernelGGL(k_maxpool,dim3(256),   dim3(256), 0, stream, d_out, d_out, flag);
}

// Round 5
// 12861.829 us; speedup vs baseline: 1.6248x; 1.6248x over previous
//
#include <hip/hip_runtime.h>
#include <hip/hip_bf16.h>

// EncoderBiLSTMMaxPool — round 5: round-3 structure, spill actually eliminated.
// k_recur: 8 WGs (stream = chain q × dir d), 512 threads, launch_bounds(512,1) -> 256 VGPR cap.
// Thread (j, half) owns gates {2*half, 2*half+1} of unit j: k<192 in 192 VGPRs, k in [192,256)
// in 128 KB LDS (b128 stride-16 conflict-free). Single-CU streams: no cross-WG sync (round 4's
// agent-scope exchange cost ~1 us/step — reverted).

typedef _Float16 f16;
typedef _Float16 h2_t  __attribute__((ext_vector_type(2)));
typedef _Float16 f16x8 __attribute__((ext_vector_type(8)));
typedef float    f32x4 __attribute__((ext_vector_type(4)));

#define B_  128
#define S_  128
#define H_  512
#define HH_ 256
#define M_  (B_ * S_)   // 16384
#define NG  1024        // gates per direction (4*HH)
#define K0  512         // LSTM input dim

__device__ __forceinline__ float sigmoidf_(float x) { return 1.0f / (1.0f + __expf(-x)); }
__device__ __forceinline__ float tanhf_(float x)    { return 1.0f - 2.0f / (__expf(2.0f * x) + 1.0f); }

__device__ __forceinline__ float ldf(const void* p, long i, int isbf) {
    return isbf ? __bfloat162float(((const __hip_bfloat16*)p)[i]) : ((const float*)p)[i];
}

__device__ __forceinline__ float dot2f(int w, int h, float acc) {
#if __has_builtin(__builtin_amdgcn_fdot2)
    return __builtin_amdgcn_fdot2(__builtin_bit_cast(h2_t, w), __builtin_bit_cast(h2_t, h), acc, false);
#else
    h2_t a = __builtin_bit_cast(h2_t, w), b = __builtin_bit_cast(h2_t, h);
    return acc + (float)a[0] * (float)b[0] + (float)a[1] * (float)b[1];
#endif
}

// ---------------- dtype detection (bf16 vs fp32 input buffers) ----------------
__global__ void k_detect(const unsigned short* __restrict__ e, int* __restrict__ flag) {
    __shared__ int cnt;
    if (threadIdx.x == 0) cnt = 0;
    __syncthreads();
    unsigned short v = e[threadIdx.x];
    int ex = (v >> 7) & 0xFF;
    if (ex >= 100 && ex < 127) atomicAdd(&cnt, 1);
    __syncthreads();
    if (threadIdx.x == 0) *flag = (cnt >= 200) ? 1 : 0;   // 1 = bf16, 0 = fp32
}

// ---------------- embedding ----------------
__global__ void k_embed(const int* __restrict__ rt, const int* __restrict__ re, const int* __restrict__ rm,
                        const void* __restrict__ Ert, const void* __restrict__ Ere,
                        const void* __restrict__ Erm, f16* __restrict__ emb,
                        const int* __restrict__ flag) {
    const int isbf = *flag;
    int gid = blockIdx.x * 256 + threadIdx.x;      // < 16384*512
    int bs = gid >> 9, h = gid & 511;
    float v = ldf(Ert, (long)rt[bs] * H_ + h, isbf)
            + ldf(Ere, (long)re[bs] * H_ + h, isbf)
            + ldf(Erm, (long)rm[bs] * H_ + h, isbf);
    emb[gid] = (f16)v;
}

// ---------------- weight conversion -> f16, bias = bih+bhh (f32) ----------------
__global__ void k_wconv(const void* __restrict__ Wih, const void* __restrict__ Whh,
                        const void* __restrict__ bih, const void* __restrict__ bhh,
                        f16* __restrict__ wih, f16* __restrict__ whh, float* __restrict__ bias,
                        const int* __restrict__ flag) {
    const int isbf = *flag;
    int gid = blockIdx.x * 256 + threadIdx.x;      // < 2,097,152
    wih[gid] = (f16)ldf(Wih, gid, isbf);
    if (gid < 1048576) whh[gid] = (f16)ldf(Whh, gid, isbf);
    if (gid < 4096)    bias[gid] = ldf(bih, gid, isbf) + ldf(bhh, gid, isbf);
}

// ---------------- GEMM: C[16384][2048] = A[16384][512] * W[2048][512]^T (f16, fp32 acc) ----------------
__global__ __launch_bounds__(256) void k_gemm(const f16* __restrict__ A, const f16* __restrict__ Bm,
                                              f16* __restrict__ C) {
    const int bm = blockIdx.x & 127;
    const int bn = blockIdx.x >> 7;
    const int tid = threadIdx.x;
    const int lane = tid & 63, wave = tid >> 6;
    const int wm = wave & 1, wn = wave >> 1;
    __shared__ __align__(16) f16 As[128][72];
    __shared__ __align__(16) f16 Bs[128][72];
    f32x4 acc[4][4];
#pragma unroll
    for (int i = 0; i < 4; ++i)
#pragma unroll
        for (int jj = 0; jj < 4; ++jj) acc[i][jj] = (f32x4){0.f, 0.f, 0.f, 0.f};
    const long abase = (long)bm * 128 * K0;
    const long bbase = (long)bn * 128 * K0;
    for (int kt = 0; kt < K0; kt += 64) {
#pragma unroll
        for (int p = 0; p < 4; ++p) {
            int r = p * 32 + (tid >> 3), s = tid & 7;
            *(int4*)&As[r][s * 8] = *(const int4*)(A  + abase + (long)r * K0 + kt + s * 8);
            *(int4*)&Bs[r][s * 8] = *(const int4*)(Bm + bbase + (long)r * K0 + kt + s * 8);
        }
        __syncthreads();
        const int quad = lane >> 4, l15 = lane & 15;
#pragma unroll
        for (int kc = 0; kc < 64; kc += 32) {
            f16x8 af[4], bf[4];
#pragma unroll
            for (int mt = 0; mt < 4; ++mt) af[mt] = *(const f16x8*)&As[wm * 64 + mt * 16 + l15][kc + quad * 8];
#pragma unroll
            for (int nt = 0; nt < 4; ++nt) bf[nt] = *(const f16x8*)&Bs[wn * 64 + nt * 16 + l15][kc + quad * 8];
#pragma unroll
            for (int mt = 0; mt < 4; ++mt)
#pragma unroll
                for (int nt = 0; nt < 4; ++nt)
                    acc[mt][nt] = __builtin_amdgcn_mfma_f32_16x16x32_f16(af[mt], bf[nt], acc[mt][nt], 0, 0, 0);
        }
        __syncthreads();
    }
    const int quad = lane >> 4, l15 = lane & 15;
#pragma unroll
    for (int mt = 0; mt < 4; ++mt)
#pragma unroll
        for (int nt = 0; nt < 4; ++nt)
#pragma unroll
            for (int r = 0; r < 4; ++r) {
                int row = bm * 128 + wm * 64 + mt * 16 + quad * 4 + r;
                int col = bn * 128 + wn * 64 + nt * 16 + l15;
                C[(long)row * 2048 + col] = (f16)acc[mt][nt][r];
            }
}

// ---------------- recurrence: 8 WGs = (chain q, dir d), 512 threads, 1 WG/CU.
// thread (j = tid&255, half = tid>>8) owns gates G0=2*half, G1=2*half+1 of unit j.
// Per gate: k<192 in VGPRs (w4, 48 int4 = 192 VGPRs), k>=192 in LDS. half==0 finalizes c,h. ----------------
__global__ __launch_bounds__(512, 1) void k_recur(
    const f16* __restrict__ xp,    // [16384][2048] input projections (no bias)
    const f16* __restrict__ whh,   // [2][2][1024][256] f16
    const float* __restrict__ bias,// [2][2][1024]
    const void* __restrict__ h0, const void* __restrict__ c0,
    f16* __restrict__ yf16,        // layer0 out [16384][512]
    void* __restrict__ yout,       // layer1 out (d_out bilstm region)
    int layer, const int* __restrict__ flag) {
    const int isbf = *flag;
    const int q = blockIdx.x >> 1, d = blockIdx.x & 1;
    const int tid = threadIdx.x;
    const int j = tid & 255, half = tid >> 8;
    const int G0 = half * 2, G1 = G0 + 1;
    const int ld = layer * 2 + d;
    const f16* wrow0 = whh + (long)ld * NG * 256;

    __shared__ __align__(16) f16 hbuf[2][256];
    __shared__ int4 wlds4[2][2][8][256];           // [half][gg][chunk][unit] = k in [192,256), 128 KB
    __shared__ float2 plds[256];                   // g,o preacts from half==1

    // stage weights: 24 int4 chunks (k<192) per gate into regs, 8 chunks into LDS
    int4 w4[2][24];
    {
        const int4* r0 = (const int4*)(wrow0 + (long)(G0 * 256 + j) * 256);
        const int4* r1 = (const int4*)(wrow0 + (long)(G1 * 256 + j) * 256);
#pragma unroll
        for (int c = 0; c < 24; ++c) { w4[0][c] = r0[c]; w4[1][c] = r1[c]; }
#pragma unroll
        for (int c = 0; c < 8; ++c) {
            wlds4[half][0][c][j] = r0[24 + c];
            wlds4[half][1][c][j] = r1[24 + c];
        }
    }
    const float b0 = bias[ld * NG + G0 * 256 + j];
    const float b1 = bias[ld * NG + G1 * 256 + j];

    float cst = 0.f;
    if (half == 0) {
        float hv = 0.f;
        if (q == 0) {                               // chain 0 starts from h0/c0; others from reset
            cst = ldf(c0, ld * 256 + j, isbf);
            hv  = ldf(h0, ld * 256 + j, isbf);
        }
        hbuf[0][j] = (f16)hv;
    }
    __syncthreads();

    int cur = 0;
    for (int step = 0; step < 4096; ++step) {
        const int b = q * 32 + (step >> 7);
        const int ti = step & 127;
        const int t = d ? (127 - ti) : ti;
        const f16* xr = xp + ((long)b * 128 + t) * 2048 + d * NG + j;
        f16 px0h = xr[G0 * 256];                    // loads hidden under the dot loop (vmcnt)
        f16 px1h = xr[G1 * 256];

        float a0 = b0, a1 = b1;
        const int4* hp = (const int4*)hbuf[cur];
        // k < 192: register weights, h staged in blocks of 4 chunks (bounded pressure)
#pragma unroll
        for (int blk = 0; blk < 6; ++blk) {
            int4 hh[4];
#pragma unroll
            for (int u = 0; u < 4; ++u) hh[u] = hp[blk * 4 + u];
#pragma unroll
            for (int u = 0; u < 4; ++u) {
                int4 wa = w4[0][blk * 4 + u], wb = w4[1][blk * 4 + u];
                a0 = dot2f(wa.x, hh[u].x, a0); a0 = dot2f(wa.y, hh[u].y, a0);
                a0 = dot2f(wa.z, hh[u].z, a0); a0 = dot2f(wa.w, hh[u].w, a0);
                a1 = dot2f(wb.x, hh[u].x, a1); a1 = dot2f(wb.y, hh[u].y, a1);
                a1 = dot2f(wb.z, hh[u].z, a1); a1 = dot2f(wb.w, hh[u].w, a1);
            }
        }
        // k in [192,256): LDS weights (b128 stride-16, conflict-free)
#pragma unroll
        for (int c = 0; c < 8; ++c) {
            int4 hh = hp[24 + c];
            int4 wa = wlds4[half][0][c][j];
            int4 wb = wlds4[half][1][c][j];
            a0 = dot2f(wa.x, hh.x, a0); a0 = dot2f(wa.y, hh.y, a0);
            a0 = dot2f(wa.z, hh.z, a0); a0 = dot2f(wa.w, hh.w, a0);
            a1 = dot2f(wb.x, hh.x, a1); a1 = dot2f(wb.y, hh.y, a1);
            a1 = dot2f(wb.z, hh.z, a1); a1 = dot2f(wb.w, hh.w, a1);
        }
        a0 += (float)px0h;
        a1 += (float)px1h;

        if (half) plds[j] = make_float2(a0, a1);    // g, o preacts (bias+xp included)
        __syncthreads();                            // B1: preacts exchanged
        if (!half) {
            float2 go = plds[j];
            float ig = sigmoidf_(a0);               // gate i
            float fg = sigmoidf_(a1);               // gate f
            float gg = tanhf_(go.x);                // gate g
            float og = sigmoidf_(go.y);             // gate o
            cst = fg * cst + ig * gg;
            float hn = og * tanhf_(cst);
            hbuf[cur ^ 1][j] = (f16)hn;
            long oidx = ((long)b * 128 + t) * 512 + d * 256 + j;
            if (layer == 0) {
                yf16[oidx] = (f16)hn;
            } else {
                if (isbf) ((__hip_bfloat16*)yout)[oidx] = __float2bfloat16(hn);
                else      ((float*)yout)[oidx] = hn;
            }
        }
        cur ^= 1;
        __syncthreads();                            // B2: hbuf[cur] ready for all
    }
}

// ---------------- max over batch axis ----------------
__global__ void k_maxpool(const void* __restrict__ bil, void* __restrict__ outbase,
                          const int* __restrict__ flag) {
    const int isbf = *flag;
    int gid = blockIdx.x * 256 + threadIdx.x;      // s*512+h, < 65536
    float m = -1e30f;
    for (int b = 0; b < 128; ++b)
        m = fmaxf(m, ldf(bil, (long)b * 65536 + gid, isbf));
    long o = (long)M_ * H_ + gid;
    if (isbf) ((__hip_bfloat16*)outbase)[o] = __float2bfloat16(m);
    else      ((float*)outbase)[o] = m;
}

extern "C" void kernel_launch(void* const* d_in, const int* in_sizes, int n_in,
                              void* d_out, int out_size, void* d_ws, size_t ws_size,
                              hipStream_t stream) {
    const int* rt = (const int*)d_in[0];
    const int* re = (const int*)d_in[1];
    const int* rm = (const int*)d_in[2];
    const void* h0  = d_in[3];
    const void* c0  = d_in[4];
    const void* Ert = d_in[5];
    const void* Ere = d_in[6];
    const void* Erm = d_in[7];
    const void* Wih = d_in[8];
    const void* Whh = d_in[9];
    const void* bih = d_in[10];
    const void* bhh = d_in[11];

    if (ws_size < 106971200u) return;

    char* ws = (char*)d_ws;
    f16*   emb  = (f16*)(ws);                      // 16,777,216 B
    f16*   wih  = (f16*)(ws + 16777216);           //  4,194,304 B  [2][2][1024][512]
    f16*   whh  = (f16*)(ws + 20971520);           //  2,097,152 B  [2][2][1024][256]
    float* bias = (float*)(ws + 23068672);         //     16,384 B  [2][2][1024]
    f16*   xpb  = (f16*)(ws + 23085056);           // 67,108,864 B  [16384][2048]
    f16*   y0   = (f16*)(ws + 90193920);           // 16,777,216 B  [16384][512]
    int*   flag = (int*)(ws + 106971136);          //          4 B

    hipLaunchKernelGGL(k_detect, dim3(1),     dim3(256), 0, stream, (const unsigned short*)Ert, flag);
    hipLaunchKernelGGL(k_embed,  dim3(32768), dim3(256), 0, stream, rt, re, rm, Ert, Ere, Erm, emb, flag);
    hipLaunchKernelGGL(k_wconv,  dim3(8192),  dim3(256), 0, stream, Wih, Whh, bih, bhh, wih, whh, bias, flag);
    hipLaunchKernelGGL(k_gemm,   dim3(2048),  dim3(256), 0, stream, emb, wih, xpb);
    hipLaunchKernelGGL(k_recur,  dim3(8),     dim3(512), 0, stream, xpb, whh, bias, h0, c0, y0, d_out, 0, flag);
    hipLaunchKernelGGL(k_gemm,   dim3(2048),  dim3(256), 0, stream, y0, wih + (long)2 * NG * K0, xpb);
    hipLaunchKernelGGL(k_recur,  dim3(8),     dim3(512), 0, stream, xpb, whh, bias, h0, c0, y0, d_out, 1, flag);
    hipLaunchKernelGGL(k_maxpool,dim3(256),   dim3(256), 0, stream, d_out, d_out, flag);
}